// Round 3
// baseline (262.122 us; speedup 1.0000x reference)
//
#include <hip/hip_runtime.h>
#include <cmath>
#include <complex>
#include <algorithm>
#include <vector>

#define NEDGES 16384
#define INDIM  240
#define SHDIM  9
#define OUTDIM 240
#define WNUM   13824

// Flat concatenated (pw-scaled) real Wigner-3j tensors for the 11 paths.
struct TPConsts { float C[363]; };

// ---------------- host: exact transliteration of the reference ----------------
static double factd(int n){ double r=1.0; for(int i=2;i<=n;++i) r*= (double)i; return r; }

static double su2_cg_coeff(int j1,int m1,int j2,int m2,int j3,int m3){
    if(m3 != m1+m2) return 0.0;
    int vmin = std::max(std::max(-j1+j2+m3, -j1+m1), 0);
    int vmax = std::min(std::min(j2+j3+m1, j3-j1+j2), j3+m3);
    double C = std::sqrt((double)(2*j3+1)*factd(j3+j1-j2)*factd(j3-j1+j2)*factd(j1+j2-j3)
               *factd(j3+m3)*factd(j3-m3)
               /(factd(j1+j2+j3+1)*factd(j1-m1)*factd(j1+m1)*factd(j2-m2)*factd(j2+m2)));
    double S=0.0;
    for(int v=vmin; v<=vmax; ++v){
        double sgn = ((v+j2+m2)&1) ? -1.0 : 1.0;
        S += sgn * factd(j2+j3+m1-v)*factd(j1-m1+v)
             /(factd(v)*factd(j3-j1+j2-v)*factd(j3+m3-v)*factd(v+j1-j2-m3));
    }
    return C*S;
}

static void real_to_complex(int l, std::complex<double>* q){
    int d=2*l+1;
    for(int i=0;i<d*d;++i) q[i]=std::complex<double>(0,0);
    const double s = 1.0/std::sqrt(2.0);
    const std::complex<double> I(0.0,1.0);
    for(int m=-l;m<=-1;++m){
        q[(l+m)*d + (l-m)] = s;
        q[(l+m)*d + (l+m)] = -I*s;
    }
    q[l*d+l]=1.0;
    for(int m=1;m<=l;++m){
        double sg = (m&1) ? -1.0 : 1.0;
        q[(l+m)*d + (l+m)] = sg*s;
        q[(l+m)*d + (l-m)] = I*sg*s;
    }
    std::complex<double> ph(1.0,0.0);
    for(int t=0;t<l;++t) ph *= std::complex<double>(0.0,-1.0);  // (-i)^l
    for(int i=0;i<d*d;++i) q[i]*=ph;
}

static void wigner3j(int l1,int l2,int l3, float* out, double scale){
    int d1=2*l1+1, d2=2*l2+1, d3=2*l3+1;
    std::vector<double> cg((size_t)d1*d2*d3, 0.0);
    for(int m1=-l1;m1<=l1;++m1)
        for(int m2=-l2;m2<=l2;++m2){
            int m3=m1+m2;
            if(std::abs(m3)<=l3)
                cg[((size_t)(l1+m1)*d2 + (l2+m2))*d3 + (l3+m3)] = su2_cg_coeff(l1,m1,l2,m2,l3,m3);
        }
    std::vector<std::complex<double>> Q1((size_t)d1*d1), Q2((size_t)d2*d2), Q3((size_t)d3*d3);
    real_to_complex(l1,Q1.data());
    real_to_complex(l2,Q2.data());
    real_to_complex(l3,Q3.data());
    std::vector<double> Cr((size_t)d1*d2*d3, 0.0);
    for(int j=0;j<d1;++j) for(int l=0;l<d2;++l) for(int m=0;m<d3;++m){
        std::complex<double> s(0,0);
        for(int i=0;i<d1;++i) for(int k=0;k<d2;++k) for(int n=0;n<d3;++n){
            double c = cg[((size_t)i*d2+k)*d3+n];
            if(c!=0.0) s += Q1[(size_t)i*d1+j]*Q2[(size_t)k*d2+l]*std::conj(Q3[(size_t)m*d3+n])*c;
        }
        Cr[((size_t)j*d2+l)*d3+m] = s.real();
    }
    double nrm=0.0; for(double x: Cr) nrm += x*x; nrm = std::sqrt(nrm);
    for(size_t i=0;i<Cr.size();++i) out[i] = (float)(Cr[i]/nrm*scale);
}

static void build_consts(TPConsts* cc){
    const double pw0 = std::sqrt(1.0/112.0);   // i3=0
    const double pw1 = std::sqrt(3.0/144.0);   // i3=1
    const double pw2 = std::sqrt(5.0/128.0);   // i3=2
    wigner3j(0,0,0, cc->C+0,   pw0);
    wigner3j(0,1,1, cc->C+1,   pw1);
    wigner3j(0,2,2, cc->C+10,  pw2);
    wigner3j(1,0,1, cc->C+35,  pw1);
    wigner3j(1,1,0, cc->C+44,  pw0);
    wigner3j(1,1,2, cc->C+53,  pw2);
    wigner3j(1,2,1, cc->C+98,  pw1);
    wigner3j(2,0,2, cc->C+143, pw2);
    wigner3j(2,1,1, cc->C+168, pw1);
    wigner3j(2,2,0, cc->C+213, pw0);
    wigner3j(2,2,2, cc->C+238, pw2);
}

// ---------------- device ----------------
// A-phase: A[u,k] = sum_i u1[u,i] * (sum_j C[i,j,k] v[j]); 64 workers (one wave).
template<int L1,int L2,int L3,int MUL1>
__device__ __forceinline__ void compute_A(const float* __restrict__ Cp,
        const float* __restrict__ urow, const float* __restrict__ vrow,
        float* __restrict__ As, int worker){
    constexpr int D1=2*L1+1, D2=2*L2+1, K=2*L3+1;
    float vv[D2];
    #pragma unroll
    for(int j=0;j<D2;++j) vv[j]=vrow[j];
    float B[D1][K];
    #pragma unroll
    for(int i=0;i<D1;++i){
        #pragma unroll
        for(int k=0;k<K;++k){
            float b=0.f;
            #pragma unroll
            for(int j=0;j<D2;++j) b = fmaf(Cp[(i*D2+j)*K+k], vv[j], b);
            B[i][k]=b;
        }
    }
    constexpr int N = MUL1*K;
    #pragma unroll 1
    for(int e=worker; e<N; e+=64){
        int uu = e/K, k = e - uu*K;
        float a=0.f;
        #pragma unroll
        for(int i=0;i<D1;++i) a = fmaf(urow[uu*D1+i], B[i][k], a);
        As[e]=a;
    }
}

// Linear weight-stream sweep over one path segment.
// Lane l reads wseg[256t + 4l]; its w-quad is fixed: w = 4*(l % (MUL3/4)) + c.
// u = (256/MUL3)*t + l/(MUL3/4). acc[c][k] += W[u, 4q+c] * A[u,k].
template<int ITERS,int MUL3,int K>
__device__ __forceinline__ void sweep(const float* __restrict__ wseg,
        const float* __restrict__ Arow, int lane, float (&acc)[4][K]){
    constexpr int GROUPS = 256/MUL3;
    const int g = lane/(MUL3/4);
    #pragma unroll
    for(int t=0;t<ITERS;++t){
        const float4 wv = *reinterpret_cast<const float4*>(wseg + t*256 + 4*lane);
        const int u = GROUPS*t + g;
        #pragma unroll
        for(int k=0;k<K;++k){
            const float a = Arow[u*K+k];
            acc[0][k] = fmaf(wv.x, a, acc[0][k]);
            acc[1][k] = fmaf(wv.y, a, acc[1][k]);
            acc[2][k] = fmaf(wv.z, a, acc[2][k]);
            acc[3][k] = fmaf(wv.w, a, acc[3][k]);
        }
    }
}

template<int K>
__device__ __forceinline__ void reduce_acc(float (&acc)[4][K], int firstmask){
    for(int m=firstmask; m<=32; m<<=1){
        #pragma unroll
        for(int c=0;c<4;++c)
            #pragma unroll
            for(int k=0;k<K;++k)
                acc[c][k] += __shfl_xor(acc[c][k], m);
    }
}

__global__ __launch_bounds__(256, 4)
void tp_kernel(const float* __restrict__ U, const float* __restrict__ V,
               const float* __restrict__ W, float* __restrict__ Out, TPConsts cc){
    __shared__ float As[4*1184];
    const int tid = threadIdx.x, blk = blockIdx.x;
    const int lane = tid&63, wave = tid>>6;

    // ---- A-phase: each wave computes A for its own edge ----
    const int z = blk*4 + wave;
    {
        const float* urow = U + (size_t)z*INDIM;
        const float* vrow = V + (size_t)z*SHDIM;
        float* A = As + wave*1184;
        compute_A<0,0,0,64>(cc.C+0,   urow,     vrow,   A+0,    lane);
        compute_A<0,1,1,64>(cc.C+1,   urow,     vrow+1, A+64,   lane);
        compute_A<0,2,2,64>(cc.C+10,  urow,     vrow+4, A+256,  lane);
        compute_A<1,0,1,32>(cc.C+35,  urow+64,  vrow,   A+576,  lane);
        compute_A<1,1,0,32>(cc.C+44,  urow+64,  vrow+1, A+672,  lane);
        compute_A<1,1,2,32>(cc.C+53,  urow+64,  vrow+1, A+704,  lane);
        compute_A<1,2,1,32>(cc.C+98,  urow+64,  vrow+4, A+864,  lane);
        compute_A<2,0,2,16>(cc.C+143, urow+160, vrow,   A+960,  lane);
        compute_A<2,1,1,16>(cc.C+168, urow+160, vrow+1, A+1040, lane);
        compute_A<2,2,0,16>(cc.C+213, urow+160, vrow+4, A+1088, lane);
        compute_A<2,2,2,16>(cc.C+238, urow+160, vrow+4, A+1104, lane);
    }
    __syncthreads();

    // ---- main: one wave streams one edge's full weight row linearly ----
    const float* wrow = W + (size_t)z*WNUM;
    const float* A    = As + wave*1184;

    float acc0[4][1] = {};   // i3=0 (l3=0): lane's w-quad = 4*(lane&15)
    float acc1[4][3] = {};   // i3=1 (l3=1): w-quad = 4*(lane&7)
    float acc2[4][5] = {};   // i3=2 (l3=2): w-quad = 4*(lane&3)

    sweep<16,64,1>(wrow+0,     A+0,    lane, acc0);   // p0 (0,0,0)
    sweep< 8,32,3>(wrow+4096,  A+64,   lane, acc1);   // p1 (0,1,1)
    sweep< 4,16,5>(wrow+6144,  A+256,  lane, acc2);   // p2 (0,2,2)
    sweep< 4,32,3>(wrow+7168,  A+576,  lane, acc1);   // p3 (1,0,1)
    sweep< 8,64,1>(wrow+8192,  A+672,  lane, acc0);   // p4 (1,1,0)
    sweep< 2,16,5>(wrow+10240, A+704,  lane, acc2);   // p5 (1,1,2)
    sweep< 4,32,3>(wrow+10752, A+864,  lane, acc1);   // p6 (1,2,1)
    sweep< 1,16,5>(wrow+11776, A+960,  lane, acc2);   // p7 (2,0,2)
    sweep< 2,32,3>(wrow+12032, A+1040, lane, acc1);   // p8 (2,1,1)
    sweep< 4,64,1>(wrow+12544, A+1088, lane, acc0);   // p9 (2,2,0)
    sweep< 1,16,5>(wrow+13568, A+1104, lane, acc2);   // p10 (2,2,2)

    // ---- fold lane-groups (u-dim splits) ----
    reduce_acc<1>(acc0, 16);   // 4 groups of 16
    reduce_acc<3>(acc1, 8);    // 8 groups of 8
    reduce_acc<5>(acc2, 4);    // 16 groups of 4

    // ---- stores ----
    float* orow = Out + (size_t)z*OUTDIM;
    if(lane < 16){
        float4 o; o.x=acc0[0][0]; o.y=acc0[1][0]; o.z=acc0[2][0]; o.w=acc0[3][0];
        *reinterpret_cast<float4*>(orow + lane*4) = o;
    }
    if(lane < 8){
        float* o = orow + 64 + lane*12;   // layout (4q+c)*3+k = 12q + 3c + k
        float4 f0, f1, f2;
        f0.x=acc1[0][0]; f0.y=acc1[0][1]; f0.z=acc1[0][2]; f0.w=acc1[1][0];
        f1.x=acc1[1][1]; f1.y=acc1[1][2]; f1.z=acc1[2][0]; f1.w=acc1[2][1];
        f2.x=acc1[2][2]; f2.y=acc1[3][0]; f2.z=acc1[3][1]; f2.w=acc1[3][2];
        *reinterpret_cast<float4*>(o+0) = f0;
        *reinterpret_cast<float4*>(o+4) = f1;
        *reinterpret_cast<float4*>(o+8) = f2;
    }
    if(lane < 4){
        float* o = orow + 160 + lane*20;  // layout (4q+c)*5+k = 20q + 5c + k
        float4 f0,f1,f2,f3;
        f0.x=acc2[0][0]; f0.y=acc2[0][1]; f0.z=acc2[0][2]; f0.w=acc2[0][3];
        f1.x=acc2[0][4]; f1.y=acc2[1][0]; f1.z=acc2[1][1]; f1.w=acc2[1][2];
        f2.x=acc2[1][3]; f2.y=acc2[1][4]; f2.z=acc2[2][0]; f2.w=acc2[2][1];
        f3.x=acc2[2][2]; f3.y=acc2[2][3]; f3.z=acc2[2][4]; f3.w=acc2[3][0];
        *reinterpret_cast<float4*>(o+0)  = f0;
        *reinterpret_cast<float4*>(o+4)  = f1;
        *reinterpret_cast<float4*>(o+8)  = f2;
        *reinterpret_cast<float4*>(o+12) = f3;
        o[16]=acc2[3][1]; o[17]=acc2[3][2]; o[18]=acc2[3][3]; o[19]=acc2[3][4];
    }
}

extern "C" void kernel_launch(void* const* d_in, const int* in_sizes, int n_in,
                              void* d_out, int out_size, void* d_ws, size_t ws_size,
                              hipStream_t stream) {
    (void)in_sizes; (void)n_in; (void)d_ws; (void)ws_size; (void)out_size;
    const float* u = (const float*)d_in[0];
    const float* v = (const float*)d_in[1];
    const float* w = (const float*)d_in[2];
    float* out = (float*)d_out;

    TPConsts cc;
    build_consts(&cc);

    tp_kernel<<<NEDGES/4, 256, 0, stream>>>(u, v, w, out, cc);
}

// Round 4
// 181.527 us; speedup vs baseline: 1.4440x; 1.4440x over previous
//
#include <hip/hip_runtime.h>
#include <cmath>
#include <complex>
#include <algorithm>
#include <vector>

#define NEDGES 16384
#define INDIM  240
#define SHDIM  9
#define OUTDIM 240
#define WNUM   13824

// Flat concatenated (pw-scaled) real Wigner-3j tensors for the 11 paths.
struct TPConsts { float C[363]; };

// ---------------- host: exact transliteration of the reference ----------------
static double factd(int n){ double r=1.0; for(int i=2;i<=n;++i) r*= (double)i; return r; }

static double su2_cg_coeff(int j1,int m1,int j2,int m2,int j3,int m3){
    if(m3 != m1+m2) return 0.0;
    int vmin = std::max(std::max(-j1+j2+m3, -j1+m1), 0);
    int vmax = std::min(std::min(j2+j3+m1, j3-j1+j2), j3+m3);
    double C = std::sqrt((double)(2*j3+1)*factd(j3+j1-j2)*factd(j3-j1+j2)*factd(j1+j2-j3)
               *factd(j3+m3)*factd(j3-m3)
               /(factd(j1+j2+j3+1)*factd(j1-m1)*factd(j1+m1)*factd(j2-m2)*factd(j2+m2)));
    double S=0.0;
    for(int v=vmin; v<=vmax; ++v){
        double sgn = ((v+j2+m2)&1) ? -1.0 : 1.0;
        S += sgn * factd(j2+j3+m1-v)*factd(j1-m1+v)
             /(factd(v)*factd(j3-j1+j2-v)*factd(j3+m3-v)*factd(v+j1-j2-m3));
    }
    return C*S;
}

static void real_to_complex(int l, std::complex<double>* q){
    int d=2*l+1;
    for(int i=0;i<d*d;++i) q[i]=std::complex<double>(0,0);
    const double s = 1.0/std::sqrt(2.0);
    const std::complex<double> I(0.0,1.0);
    for(int m=-l;m<=-1;++m){
        q[(l+m)*d + (l-m)] = s;
        q[(l+m)*d + (l+m)] = -I*s;
    }
    q[l*d+l]=1.0;
    for(int m=1;m<=l;++m){
        double sg = (m&1) ? -1.0 : 1.0;
        q[(l+m)*d + (l+m)] = sg*s;
        q[(l+m)*d + (l-m)] = I*sg*s;
    }
    std::complex<double> ph(1.0,0.0);
    for(int t=0;t<l;++t) ph *= std::complex<double>(0.0,-1.0);  // (-i)^l
    for(int i=0;i<d*d;++i) q[i]*=ph;
}

static void wigner3j(int l1,int l2,int l3, float* out, double scale){
    int d1=2*l1+1, d2=2*l2+1, d3=2*l3+1;
    std::vector<double> cg((size_t)d1*d2*d3, 0.0);
    for(int m1=-l1;m1<=l1;++m1)
        for(int m2=-l2;m2<=l2;++m2){
            int m3=m1+m2;
            if(std::abs(m3)<=l3)
                cg[((size_t)(l1+m1)*d2 + (l2+m2))*d3 + (l3+m3)] = su2_cg_coeff(l1,m1,l2,m2,l3,m3);
        }
    std::vector<std::complex<double>> Q1((size_t)d1*d1), Q2((size_t)d2*d2), Q3((size_t)d3*d3);
    real_to_complex(l1,Q1.data());
    real_to_complex(l2,Q2.data());
    real_to_complex(l3,Q3.data());
    std::vector<double> Cr((size_t)d1*d2*d3, 0.0);
    for(int j=0;j<d1;++j) for(int l=0;l<d2;++l) for(int m=0;m<d3;++m){
        std::complex<double> s(0,0);
        for(int i=0;i<d1;++i) for(int k=0;k<d2;++k) for(int n=0;n<d3;++n){
            double c = cg[((size_t)i*d2+k)*d3+n];
            if(c!=0.0) s += Q1[(size_t)i*d1+j]*Q2[(size_t)k*d2+l]*std::conj(Q3[(size_t)m*d3+n])*c;
        }
        Cr[((size_t)j*d2+l)*d3+m] = s.real();
    }
    double nrm=0.0; for(double x: Cr) nrm += x*x; nrm = std::sqrt(nrm);
    for(size_t i=0;i<Cr.size();++i) out[i] = (float)(Cr[i]/nrm*scale);
}

static void build_consts(TPConsts* cc){
    const double pw0 = std::sqrt(1.0/112.0);   // i3=0
    const double pw1 = std::sqrt(3.0/144.0);   // i3=1
    const double pw2 = std::sqrt(5.0/128.0);   // i3=2
    wigner3j(0,0,0, cc->C+0,   pw0);
    wigner3j(0,1,1, cc->C+1,   pw1);
    wigner3j(0,2,2, cc->C+10,  pw2);
    wigner3j(1,0,1, cc->C+35,  pw1);
    wigner3j(1,1,0, cc->C+44,  pw0);
    wigner3j(1,1,2, cc->C+53,  pw2);
    wigner3j(1,2,1, cc->C+98,  pw1);
    wigner3j(2,0,2, cc->C+143, pw2);
    wigner3j(2,1,1, cc->C+168, pw1);
    wigner3j(2,2,0, cc->C+213, pw0);
    wigner3j(2,2,2, cc->C+238, pw2);
}

// ---------------- device ----------------
// B-phase: lanes 0..D1*K-1 each compute B[i,k] = sum_j C[i,j,k] v[j] -> LDS
template<int L1,int L2,int L3>
__device__ __forceinline__ void compute_B(const float* __restrict__ Cp,
        const float* __restrict__ vrow, float* __restrict__ Bp, int lane){
    constexpr int D1=2*L1+1, D2=2*L2+1, K=2*L3+1;
    if(lane < D1*K){
        const int i = lane / K, k = lane - i*K;
        float b = 0.f;
        #pragma unroll
        for(int j=0;j<D2;++j) b = fmaf(Cp[(i*D2+j)*K+k], vrow[j], b);
        Bp[lane] = b;   // layout i*K+k
    }
}

// A-phase: A[u,k] = sum_i u1[u,i] * B[i,k]; B read from LDS (same wave wrote it).
template<int L1,int L3,int MUL1>
__device__ __forceinline__ void compute_A(const float* __restrict__ Bp,
        const float* __restrict__ urow, float* __restrict__ As, int lane){
    constexpr int D1=2*L1+1, K=2*L3+1;
    constexpr int N = MUL1*K;
    #pragma unroll
    for(int e=lane; e<N; e+=64){
        int uu = e/K, k = e - uu*K;
        float a=0.f;
        #pragma unroll
        for(int i=0;i<D1;++i) a = fmaf(urow[uu*D1+i], Bp[i*K+k], a);
        As[e]=a;
    }
}

// Linear weight-stream sweep over one path segment.
// Lane l reads wseg[256t + 4l]; w-quad fixed: q = l % (MUL3/4).
// u = (256/MUL3)*t + l/(MUL3/4). acc[c][k] += W[u, 4q+c] * A[u,k].
template<int ITERS,int MUL3,int K>
__device__ __forceinline__ void sweep(const float* __restrict__ wseg,
        const float* __restrict__ Arow, int lane, float (&acc)[4][K]){
    constexpr int GROUPS = 256/MUL3;
    const int g = lane/(MUL3/4);
    #pragma unroll
    for(int t=0;t<ITERS;++t){
        const float4 wv = *reinterpret_cast<const float4*>(wseg + t*256 + 4*lane);
        const int u = GROUPS*t + g;
        #pragma unroll
        for(int k=0;k<K;++k){
            const float a = Arow[u*K+k];
            acc[0][k] = fmaf(wv.x, a, acc[0][k]);
            acc[1][k] = fmaf(wv.y, a, acc[1][k]);
            acc[2][k] = fmaf(wv.z, a, acc[2][k]);
            acc[3][k] = fmaf(wv.w, a, acc[3][k]);
        }
    }
}

template<int K>
__device__ __forceinline__ void reduce_acc(float (&acc)[4][K], int firstmask){
    for(int m=firstmask; m<=32; m<<=1){
        #pragma unroll
        for(int c=0;c<4;++c)
            #pragma unroll
            for(int k=0;k<K;++k)
                acc[c][k] += __shfl_xor(acc[c][k], m);
    }
}

__global__ __launch_bounds__(256)
void tp_kernel(const float* __restrict__ U, const float* __restrict__ V,
               const float* __restrict__ W, float* __restrict__ Out, TPConsts cc){
    __shared__ float As[4*1184];
    __shared__ float Bs[4*128];
    const int tid = threadIdx.x, blk = blockIdx.x;
    const int lane = tid&63, wave = tid>>6;

    // Each wave owns one edge end-to-end; no cross-wave dependencies, no barriers.
    const int z = blk*4 + wave;
    const float* urow = U + (size_t)z*INDIM;
    const float* vrow = V + (size_t)z*SHDIM;
    float* A  = As + wave*1184;
    float* Bw = Bs + wave*128;

    // ---- B-phase: 115 small dots distributed over lanes ----
    compute_B<0,0,0>(cc.C+0,   vrow,   Bw+0,  lane);
    compute_B<0,1,1>(cc.C+1,   vrow+1, Bw+1,  lane);
    compute_B<0,2,2>(cc.C+10,  vrow+4, Bw+4,  lane);
    compute_B<1,0,1>(cc.C+35,  vrow,   Bw+9,  lane);
    compute_B<1,1,0>(cc.C+44,  vrow+1, Bw+18, lane);
    compute_B<1,1,2>(cc.C+53,  vrow+1, Bw+21, lane);
    compute_B<1,2,1>(cc.C+98,  vrow+4, Bw+36, lane);
    compute_B<2,0,2>(cc.C+143, vrow,   Bw+45, lane);
    compute_B<2,1,1>(cc.C+168, vrow+1, Bw+70, lane);
    compute_B<2,2,0>(cc.C+213, vrow+4, Bw+85, lane);
    compute_B<2,2,2>(cc.C+238, vrow+4, Bw+90, lane);

    // ---- A-phase: 1184 elems over 64 lanes (per-wave LDS ordering guarantees B visible) ----
    compute_A<0,0,64>(Bw+0,  urow,     A+0,    lane);
    compute_A<0,1,64>(Bw+1,  urow,     A+64,   lane);
    compute_A<0,2,64>(Bw+4,  urow,     A+256,  lane);
    compute_A<1,1,32>(Bw+9,  urow+64,  A+576,  lane);
    compute_A<1,0,32>(Bw+18, urow+64,  A+672,  lane);
    compute_A<1,2,32>(Bw+21, urow+64,  A+704,  lane);
    compute_A<1,1,32>(Bw+36, urow+64,  A+864,  lane);
    compute_A<2,2,16>(Bw+45, urow+160, A+960,  lane);
    compute_A<2,1,16>(Bw+70, urow+160, A+1040, lane);
    compute_A<2,0,16>(Bw+85, urow+160, A+1088, lane);
    compute_A<2,2,16>(Bw+90, urow+160, A+1104, lane);

    // ---- main: this wave streams its edge's full weight row linearly ----
    const float* wrow = W + (size_t)z*WNUM;

    float acc0[4][1] = {};   // i3=0 (l3=0): lane's w-quad = lane&15
    float acc1[4][3] = {};   // i3=1 (l3=1): w-quad = lane&7
    float acc2[4][5] = {};   // i3=2 (l3=2): w-quad = lane&3

    sweep<16,64,1>(wrow+0,     A+0,    lane, acc0);   // p0 (0,0,0)
    sweep< 8,32,3>(wrow+4096,  A+64,   lane, acc1);   // p1 (0,1,1)
    sweep< 4,16,5>(wrow+6144,  A+256,  lane, acc2);   // p2 (0,2,2)
    sweep< 4,32,3>(wrow+7168,  A+576,  lane, acc1);   // p3 (1,0,1)
    sweep< 8,64,1>(wrow+8192,  A+672,  lane, acc0);   // p4 (1,1,0)
    sweep< 2,16,5>(wrow+10240, A+704,  lane, acc2);   // p5 (1,1,2)
    sweep< 4,32,3>(wrow+10752, A+864,  lane, acc1);   // p6 (1,2,1)
    sweep< 1,16,5>(wrow+11776, A+960,  lane, acc2);   // p7 (2,0,2)
    sweep< 2,32,3>(wrow+12032, A+1040, lane, acc1);   // p8 (2,1,1)
    sweep< 4,64,1>(wrow+12544, A+1088, lane, acc0);   // p9 (2,2,0)
    sweep< 1,16,5>(wrow+13568, A+1104, lane, acc2);   // p10 (2,2,2)

    // ---- fold lane-groups (u-dim splits) ----
    reduce_acc<1>(acc0, 16);   // 4 groups of 16
    reduce_acc<3>(acc1, 8);    // 8 groups of 8
    reduce_acc<5>(acc2, 4);    // 16 groups of 4

    // ---- stores ----
    float* orow = Out + (size_t)z*OUTDIM;
    if(lane < 16){
        float4 o; o.x=acc0[0][0]; o.y=acc0[1][0]; o.z=acc0[2][0]; o.w=acc0[3][0];
        *reinterpret_cast<float4*>(orow + lane*4) = o;
    }
    if(lane < 8){
        float* o = orow + 64 + lane*12;   // layout (4q+c)*3+k = 12q + 3c + k
        float4 f0, f1, f2;
        f0.x=acc1[0][0]; f0.y=acc1[0][1]; f0.z=acc1[0][2]; f0.w=acc1[1][0];
        f1.x=acc1[1][1]; f1.y=acc1[1][2]; f1.z=acc1[2][0]; f1.w=acc1[2][1];
        f2.x=acc1[2][2]; f2.y=acc1[3][0]; f2.z=acc1[3][1]; f2.w=acc1[3][2];
        *reinterpret_cast<float4*>(o+0) = f0;
        *reinterpret_cast<float4*>(o+4) = f1;
        *reinterpret_cast<float4*>(o+8) = f2;
    }
    if(lane < 4){
        float* o = orow + 160 + lane*20;  // layout (4q+c)*5+k = 20q + 5c + k
        float4 f0,f1,f2,f3;
        f0.x=acc2[0][0]; f0.y=acc2[0][1]; f0.z=acc2[0][2]; f0.w=acc2[0][3];
        f1.x=acc2[0][4]; f1.y=acc2[1][0]; f1.z=acc2[1][1]; f1.w=acc2[1][2];
        f2.x=acc2[1][3]; f2.y=acc2[1][4]; f2.z=acc2[2][0]; f2.w=acc2[2][1];
        f3.x=acc2[2][2]; f3.y=acc2[2][3]; f3.z=acc2[2][4]; f3.w=acc2[3][0];
        *reinterpret_cast<float4*>(o+0)  = f0;
        *reinterpret_cast<float4*>(o+4)  = f1;
        *reinterpret_cast<float4*>(o+8)  = f2;
        *reinterpret_cast<float4*>(o+12) = f3;
        o[16]=acc2[3][1]; o[17]=acc2[3][2]; o[18]=acc2[3][3]; o[19]=acc2[3][4];
    }
}

extern "C" void kernel_launch(void* const* d_in, const int* in_sizes, int n_in,
                              void* d_out, int out_size, void* d_ws, size_t ws_size,
                              hipStream_t stream) {
    (void)in_sizes; (void)n_in; (void)d_ws; (void)ws_size; (void)out_size;
    const float* u = (const float*)d_in[0];
    const float* v = (const float*)d_in[1];
    const float* w = (const float*)d_in[2];
    float* out = (float*)d_out;

    TPConsts cc;
    build_consts(&cc);

    tp_kernel<<<NEDGES/4, 256, 0, stream>>>(u, v, w, out, cc);
}

// Round 6
// 169.077 us; speedup vs baseline: 1.5503x; 1.0736x over previous
//
#include <hip/hip_runtime.h>
#include <cmath>
#include <complex>
#include <algorithm>
#include <vector>

#define NEDGES 16384
#define INDIM  240
#define SHDIM  9
#define OUTDIM 240
#define WNUM   13824

typedef float fv4 __attribute__((ext_vector_type(4)));  // native clang vector: OK for nontemporal builtins

// Flat concatenated (pw-scaled) real Wigner-3j tensors for the 11 paths.
struct TPConsts { float C[363]; };

// ---------------- host: exact transliteration of the reference ----------------
static double factd(int n){ double r=1.0; for(int i=2;i<=n;++i) r*= (double)i; return r; }

static double su2_cg_coeff(int j1,int m1,int j2,int m2,int j3,int m3){
    if(m3 != m1+m2) return 0.0;
    int vmin = std::max(std::max(-j1+j2+m3, -j1+m1), 0);
    int vmax = std::min(std::min(j2+j3+m1, j3-j1+j2), j3+m3);
    double C = std::sqrt((double)(2*j3+1)*factd(j3+j1-j2)*factd(j3-j1+j2)*factd(j1+j2-j3)
               *factd(j3+m3)*factd(j3-m3)
               /(factd(j1+j2+j3+1)*factd(j1-m1)*factd(j1+m1)*factd(j2-m2)*factd(j2+m2)));
    double S=0.0;
    for(int v=vmin; v<=vmax; ++v){
        double sgn = ((v+j2+m2)&1) ? -1.0 : 1.0;
        S += sgn * factd(j2+j3+m1-v)*factd(j1-m1+v)
             /(factd(v)*factd(j3-j1+j2-v)*factd(j3+m3-v)*factd(v+j1-j2-m3));
    }
    return C*S;
}

static void real_to_complex(int l, std::complex<double>* q){
    int d=2*l+1;
    for(int i=0;i<d*d;++i) q[i]=std::complex<double>(0,0);
    const double s = 1.0/std::sqrt(2.0);
    const std::complex<double> I(0.0,1.0);
    for(int m=-l;m<=-1;++m){
        q[(l+m)*d + (l-m)] = s;
        q[(l+m)*d + (l+m)] = -I*s;
    }
    q[l*d+l]=1.0;
    for(int m=1;m<=l;++m){
        double sg = (m&1) ? -1.0 : 1.0;
        q[(l+m)*d + (l+m)] = sg*s;
        q[(l+m)*d + (l-m)] = I*sg*s;
    }
    std::complex<double> ph(1.0,0.0);
    for(int t=0;t<l;++t) ph *= std::complex<double>(0.0,-1.0);  // (-i)^l
    for(int i=0;i<d*d;++i) q[i]*=ph;
}

static void wigner3j(int l1,int l2,int l3, float* out, double scale){
    int d1=2*l1+1, d2=2*l2+1, d3=2*l3+1;
    std::vector<double> cg((size_t)d1*d2*d3, 0.0);
    for(int m1=-l1;m1<=l1;++m1)
        for(int m2=-l2;m2<=l2;++m2){
            int m3=m1+m2;
            if(std::abs(m3)<=l3)
                cg[((size_t)(l1+m1)*d2 + (l2+m2))*d3 + (l3+m3)] = su2_cg_coeff(l1,m1,l2,m2,l3,m3);
        }
    std::vector<std::complex<double>> Q1((size_t)d1*d1), Q2((size_t)d2*d2), Q3((size_t)d3*d3);
    real_to_complex(l1,Q1.data());
    real_to_complex(l2,Q2.data());
    real_to_complex(l3,Q3.data());
    std::vector<double> Cr((size_t)d1*d2*d3, 0.0);
    for(int j=0;j<d1;++j) for(int l=0;l<d2;++l) for(int m=0;m<d3;++m){
        std::complex<double> s(0,0);
        for(int i=0;i<d1;++i) for(int k=0;k<d2;++k) for(int n=0;n<d3;++n){
            double c = cg[((size_t)i*d2+k)*d3+n];
            if(c!=0.0) s += Q1[(size_t)i*d1+j]*Q2[(size_t)k*d2+l]*std::conj(Q3[(size_t)m*d3+n])*c;
        }
        Cr[((size_t)j*d2+l)*d3+m] = s.real();
    }
    double nrm=0.0; for(double x: Cr) nrm += x*x; nrm = std::sqrt(nrm);
    for(size_t i=0;i<Cr.size();++i) out[i] = (float)(Cr[i]/nrm*scale);
}

static void build_consts(TPConsts* cc){
    const double pw0 = std::sqrt(1.0/112.0);   // i3=0
    const double pw1 = std::sqrt(3.0/144.0);   // i3=1
    const double pw2 = std::sqrt(5.0/128.0);   // i3=2
    wigner3j(0,0,0, cc->C+0,   pw0);
    wigner3j(0,1,1, cc->C+1,   pw1);
    wigner3j(0,2,2, cc->C+10,  pw2);
    wigner3j(1,0,1, cc->C+35,  pw1);
    wigner3j(1,1,0, cc->C+44,  pw0);
    wigner3j(1,1,2, cc->C+53,  pw2);
    wigner3j(1,2,1, cc->C+98,  pw1);
    wigner3j(2,0,2, cc->C+143, pw2);
    wigner3j(2,1,1, cc->C+168, pw1);
    wigner3j(2,2,0, cc->C+213, pw0);
    wigner3j(2,2,2, cc->C+238, pw2);
}

// ---------------- device ----------------
#define NTLOAD(p)  __builtin_nontemporal_load(p)

// B-phase: lanes 0..D1*K-1 each compute B[i,k] = sum_j C[i,j,k] v[j] -> LDS
template<int L1,int L2,int L3>
__device__ __forceinline__ void compute_B(const float* __restrict__ Cp,
        const float* __restrict__ vrow, float* __restrict__ Bp, int lane){
    constexpr int D1=2*L1+1, D2=2*L2+1, K=2*L3+1;
    if(lane < D1*K){
        const int i = lane / K, k = lane - i*K;
        float b = 0.f;
        #pragma unroll
        for(int j=0;j<D2;++j) b = fmaf(Cp[(i*D2+j)*K+k], vrow[j], b);
        Bp[lane] = b;   // layout i*K+k
    }
}

// A-phase: A[u,k] = sum_i u1[u,i] * B[i,k]; B read from LDS (same wave wrote it).
template<int L1,int L3,int MUL1>
__device__ __forceinline__ void compute_A(const float* __restrict__ Bp,
        const float* __restrict__ urow, float* __restrict__ As, int lane){
    constexpr int D1=2*L1+1, K=2*L3+1;
    constexpr int N = MUL1*K;
    #pragma unroll
    for(int e=lane; e<N; e+=64){
        int uu = e/K, k = e - uu*K;
        float a=0.f;
        #pragma unroll
        for(int i=0;i<D1;++i) a = fmaf(urow[uu*D1+i], Bp[i*K+k], a);
        As[e]=a;
    }
}

// Inner FMA block for one weight quad against A[u,*].
template<int K>
__device__ __forceinline__ void fma_quad(const fv4 wv,
        const float* __restrict__ Arow, int u, float (&acc)[4][K]){
    #pragma unroll
    for(int k=0;k<K;++k){
        const float a = Arow[u*K+k];
        acc[0][k] = fmaf(wv.x, a, acc[0][k]);
        acc[1][k] = fmaf(wv.y, a, acc[1][k]);
        acc[2][k] = fmaf(wv.z, a, acc[2][k]);
        acc[3][k] = fmaf(wv.w, a, acc[3][k]);
    }
}

// Linear weight-stream sweep over one path segment (nontemporal loads).
// Lane l reads wseg[256t + 4l]; w-quad fixed: q = l % (MUL3/4).
// u = (256/MUL3)*t + l/(MUL3/4). acc[c][k] += W[u, 4q+c] * A[u,k].
template<int ITERS,int MUL3,int K,int TSTART=0>
__device__ __forceinline__ void sweep(const float* __restrict__ wseg,
        const float* __restrict__ Arow, int lane, float (&acc)[4][K]){
    constexpr int GROUPS = 256/MUL3;
    const int g = lane/(MUL3/4);
    #pragma unroll
    for(int t=TSTART;t<ITERS;++t){
        const fv4 wv = NTLOAD(reinterpret_cast<const fv4*>(wseg + t*256 + 4*lane));
        fma_quad<K>(wv, Arow, GROUPS*t + g, acc);
    }
}

template<int K>
__device__ __forceinline__ void reduce_acc(float (&acc)[4][K], int firstmask){
    for(int m=firstmask; m<=32; m<<=1){
        #pragma unroll
        for(int c=0;c<4;++c)
            #pragma unroll
            for(int k=0;k<K;++k)
                acc[c][k] += __shfl_xor(acc[c][k], m);
    }
}

#define NPF 8   // prefetched float4s per wave (p0 iterations 0..NPF-1)

__global__ __launch_bounds__(256)
void tp_kernel(const float* __restrict__ U, const float* __restrict__ V,
               const float* __restrict__ W, float* __restrict__ Out, TPConsts cc){
    __shared__ float As[4*1184];
    __shared__ float Bs[4*128];
    const int tid = threadIdx.x, blk = blockIdx.x;
    const int lane = tid&63, wave = tid>>6;

    // Each wave owns one edge end-to-end; no cross-wave dependencies, no barriers.
    const int z = blk*4 + wave;
    const float* urow = U + (size_t)z*INDIM;
    const float* vrow = V + (size_t)z*SHDIM;
    const float* wrow = W + (size_t)z*WNUM;
    float* A  = As + wave*1184;
    float* Bw = Bs + wave*128;

    // ---- prefetch first NPF weight chunks so HBM stays busy through B/A phase ----
    fv4 pf[NPF];
    #pragma unroll
    for(int t=0;t<NPF;++t)
        pf[t] = NTLOAD(reinterpret_cast<const fv4*>(wrow + t*256 + 4*lane));

    // ---- B-phase: 115 small dots distributed over lanes ----
    compute_B<0,0,0>(cc.C+0,   vrow,   Bw+0,  lane);
    compute_B<0,1,1>(cc.C+1,   vrow+1, Bw+1,  lane);
    compute_B<0,2,2>(cc.C+10,  vrow+4, Bw+4,  lane);
    compute_B<1,0,1>(cc.C+35,  vrow,   Bw+9,  lane);
    compute_B<1,1,0>(cc.C+44,  vrow+1, Bw+18, lane);
    compute_B<1,1,2>(cc.C+53,  vrow+1, Bw+21, lane);
    compute_B<1,2,1>(cc.C+98,  vrow+4, Bw+36, lane);
    compute_B<2,0,2>(cc.C+143, vrow,   Bw+45, lane);
    compute_B<2,1,1>(cc.C+168, vrow+1, Bw+70, lane);
    compute_B<2,2,0>(cc.C+213, vrow+4, Bw+85, lane);
    compute_B<2,2,2>(cc.C+238, vrow+4, Bw+90, lane);

    // ---- A-phase: 1184 elems over 64 lanes (per-wave LDS ordering guarantees B visible) ----
    compute_A<0,0,64>(Bw+0,  urow,     A+0,    lane);
    compute_A<0,1,64>(Bw+1,  urow,     A+64,   lane);
    compute_A<0,2,64>(Bw+4,  urow,     A+256,  lane);
    compute_A<1,1,32>(Bw+9,  urow+64,  A+576,  lane);
    compute_A<1,0,32>(Bw+18, urow+64,  A+672,  lane);
    compute_A<1,2,32>(Bw+21, urow+64,  A+704,  lane);
    compute_A<1,1,32>(Bw+36, urow+64,  A+864,  lane);
    compute_A<2,2,16>(Bw+45, urow+160, A+960,  lane);
    compute_A<2,1,16>(Bw+70, urow+160, A+1040, lane);
    compute_A<2,0,16>(Bw+85, urow+160, A+1088, lane);
    compute_A<2,2,16>(Bw+90, urow+160, A+1104, lane);

    // ---- main: this wave streams its edge's full weight row linearly ----
    float acc0[4][1] = {};   // i3=0 (l3=0): lane's w-quad = lane&15
    float acc1[4][3] = {};   // i3=1 (l3=1): w-quad = lane&7
    float acc2[4][5] = {};   // i3=2 (l3=2): w-quad = lane&3

    // p0 (0,0,0): consume prefetched chunks, then the rest
    {
        const int g = lane/16;
        #pragma unroll
        for(int t=0;t<NPF;++t) fma_quad<1>(pf[t], A+0, 4*t + g, acc0);
    }
    sweep<16,64,1,NPF>(wrow+0, A+0,    lane, acc0);   // p0 tail
    sweep< 8,32,3>(wrow+4096,  A+64,   lane, acc1);   // p1 (0,1,1)
    sweep< 4,16,5>(wrow+6144,  A+256,  lane, acc2);   // p2 (0,2,2)
    sweep< 4,32,3>(wrow+7168,  A+576,  lane, acc1);   // p3 (1,0,1)
    sweep< 8,64,1>(wrow+8192,  A+672,  lane, acc0);   // p4 (1,1,0)
    sweep< 2,16,5>(wrow+10240, A+704,  lane, acc2);   // p5 (1,1,2)
    sweep< 4,32,3>(wrow+10752, A+864,  lane, acc1);   // p6 (1,2,1)
    sweep< 1,16,5>(wrow+11776, A+960,  lane, acc2);   // p7 (2,0,2)
    sweep< 2,32,3>(wrow+12032, A+1040, lane, acc1);   // p8 (2,1,1)
    sweep< 4,64,1>(wrow+12544, A+1088, lane, acc0);   // p9 (2,2,0)
    sweep< 1,16,5>(wrow+13568, A+1104, lane, acc2);   // p10 (2,2,2)

    // ---- fold lane-groups (u-dim splits) ----
    reduce_acc<1>(acc0, 16);   // 4 groups of 16
    reduce_acc<3>(acc1, 8);    // 8 groups of 8
    reduce_acc<5>(acc2, 4);    // 16 groups of 4

    // ---- stores (nontemporal) ----
    float* orow = Out + (size_t)z*OUTDIM;
    if(lane < 16){
        fv4 o; o.x=acc0[0][0]; o.y=acc0[1][0]; o.z=acc0[2][0]; o.w=acc0[3][0];
        __builtin_nontemporal_store(o, reinterpret_cast<fv4*>(orow + lane*4));
    }
    if(lane < 8){
        float* o = orow + 64 + lane*12;   // layout (4q+c)*3+k = 12q + 3c + k
        fv4 f0, f1, f2;
        f0.x=acc1[0][0]; f0.y=acc1[0][1]; f0.z=acc1[0][2]; f0.w=acc1[1][0];
        f1.x=acc1[1][1]; f1.y=acc1[1][2]; f1.z=acc1[2][0]; f1.w=acc1[2][1];
        f2.x=acc1[2][2]; f2.y=acc1[3][0]; f2.z=acc1[3][1]; f2.w=acc1[3][2];
        __builtin_nontemporal_store(f0, reinterpret_cast<fv4*>(o+0));
        __builtin_nontemporal_store(f1, reinterpret_cast<fv4*>(o+4));
        __builtin_nontemporal_store(f2, reinterpret_cast<fv4*>(o+8));
    }
    if(lane < 4){
        float* o = orow + 160 + lane*20;  // layout (4q+c)*5+k = 20q + 5c + k
        fv4 f0,f1,f2,f3;
        f0.x=acc2[0][0]; f0.y=acc2[0][1]; f0.z=acc2[0][2]; f0.w=acc2[0][3];
        f1.x=acc2[0][4]; f1.y=acc2[1][0]; f1.z=acc2[1][1]; f1.w=acc2[1][2];
        f2.x=acc2[1][3]; f2.y=acc2[1][4]; f2.z=acc2[2][0]; f2.w=acc2[2][1];
        f3.x=acc2[2][2]; f3.y=acc2[2][3]; f3.z=acc2[2][4]; f3.w=acc2[3][0];
        __builtin_nontemporal_store(f0, reinterpret_cast<fv4*>(o+0));
        __builtin_nontemporal_store(f1, reinterpret_cast<fv4*>(o+4));
        __builtin_nontemporal_store(f2, reinterpret_cast<fv4*>(o+8));
        __builtin_nontemporal_store(f3, reinterpret_cast<fv4*>(o+12));
        o[16]=acc2[3][1]; o[17]=acc2[3][2]; o[18]=acc2[3][3]; o[19]=acc2[3][4];
    }
}

extern "C" void kernel_launch(void* const* d_in, const int* in_sizes, int n_in,
                              void* d_out, int out_size, void* d_ws, size_t ws_size,
                              hipStream_t stream) {
    (void)in_sizes; (void)n_in; (void)d_ws; (void)ws_size; (void)out_size;
    const float* u = (const float*)d_in[0];
    const float* v = (const float*)d_in[1];
    const float* w = (const float*)d_in[2];
    float* out = (float*)d_out;

    TPConsts cc;
    build_consts(&cc);

    tp_kernel<<<NEDGES/4, 256, 0, stream>>>(u, v, w, out, cc);
}

// Round 7
// 168.898 us; speedup vs baseline: 1.5520x; 1.0011x over previous
//
#include <hip/hip_runtime.h>
#include <cmath>
#include <complex>
#include <algorithm>
#include <vector>

#define NEDGES 16384
#define INDIM  240
#define SHDIM  9
#define OUTDIM 240
#define WNUM   13824

typedef float fv4 __attribute__((ext_vector_type(4)));  // native clang vector: OK for nontemporal builtins

// Flat concatenated (pw-scaled) real Wigner-3j tensors for the 11 paths.
struct TPConsts { float C[363]; };

// ---------------- host: exact transliteration of the reference ----------------
static double factd(int n){ double r=1.0; for(int i=2;i<=n;++i) r*= (double)i; return r; }

static double su2_cg_coeff(int j1,int m1,int j2,int m2,int j3,int m3){
    if(m3 != m1+m2) return 0.0;
    int vmin = std::max(std::max(-j1+j2+m3, -j1+m1), 0);
    int vmax = std::min(std::min(j2+j3+m1, j3-j1+j2), j3+m3);
    double C = std::sqrt((double)(2*j3+1)*factd(j3+j1-j2)*factd(j3-j1+j2)*factd(j1+j2-j3)
               *factd(j3+m3)*factd(j3-m3)
               /(factd(j1+j2+j3+1)*factd(j1-m1)*factd(j1+m1)*factd(j2-m2)*factd(j2+m2)));
    double S=0.0;
    for(int v=vmin; v<=vmax; ++v){
        double sgn = ((v+j2+m2)&1) ? -1.0 : 1.0;
        S += sgn * factd(j2+j3+m1-v)*factd(j1-m1+v)
             /(factd(v)*factd(j3-j1+j2-v)*factd(j3+m3-v)*factd(v+j1-j2-m3));
    }
    return C*S;
}

static void real_to_complex(int l, std::complex<double>* q){
    int d=2*l+1;
    for(int i=0;i<d*d;++i) q[i]=std::complex<double>(0,0);
    const double s = 1.0/std::sqrt(2.0);
    const std::complex<double> I(0.0,1.0);
    for(int m=-l;m<=-1;++m){
        q[(l+m)*d + (l-m)] = s;
        q[(l+m)*d + (l+m)] = -I*s;
    }
    q[l*d+l]=1.0;
    for(int m=1;m<=l;++m){
        double sg = (m&1) ? -1.0 : 1.0;
        q[(l+m)*d + (l+m)] = sg*s;
        q[(l+m)*d + (l-m)] = I*sg*s;
    }
    std::complex<double> ph(1.0,0.0);
    for(int t=0;t<l;++t) ph *= std::complex<double>(0.0,-1.0);  // (-i)^l
    for(int i=0;i<d*d;++i) q[i]*=ph;
}

static void wigner3j(int l1,int l2,int l3, float* out, double scale){
    int d1=2*l1+1, d2=2*l2+1, d3=2*l3+1;
    std::vector<double> cg((size_t)d1*d2*d3, 0.0);
    for(int m1=-l1;m1<=l1;++m1)
        for(int m2=-l2;m2<=l2;++m2){
            int m3=m1+m2;
            if(std::abs(m3)<=l3)
                cg[((size_t)(l1+m1)*d2 + (l2+m2))*d3 + (l3+m3)] = su2_cg_coeff(l1,m1,l2,m2,l3,m3);
        }
    std::vector<std::complex<double>> Q1((size_t)d1*d1), Q2((size_t)d2*d2), Q3((size_t)d3*d3);
    real_to_complex(l1,Q1.data());
    real_to_complex(l2,Q2.data());
    real_to_complex(l3,Q3.data());
    std::vector<double> Cr((size_t)d1*d2*d3, 0.0);
    for(int j=0;j<d1;++j) for(int l=0;l<d2;++l) for(int m=0;m<d3;++m){
        std::complex<double> s(0,0);
        for(int i=0;i<d1;++i) for(int k=0;k<d2;++k) for(int n=0;n<d3;++n){
            double c = cg[((size_t)i*d2+k)*d3+n];
            if(c!=0.0) s += Q1[(size_t)i*d1+j]*Q2[(size_t)k*d2+l]*std::conj(Q3[(size_t)m*d3+n])*c;
        }
        Cr[((size_t)j*d2+l)*d3+m] = s.real();
    }
    double nrm=0.0; for(double x: Cr) nrm += x*x; nrm = std::sqrt(nrm);
    for(size_t i=0;i<Cr.size();++i) out[i] = (float)(Cr[i]/nrm*scale);
}

static void build_consts(TPConsts* cc){
    const double pw0 = std::sqrt(1.0/112.0);   // i3=0
    const double pw1 = std::sqrt(3.0/144.0);   // i3=1
    const double pw2 = std::sqrt(5.0/128.0);   // i3=2
    wigner3j(0,0,0, cc->C+0,   pw0);
    wigner3j(0,1,1, cc->C+1,   pw1);
    wigner3j(0,2,2, cc->C+10,  pw2);
    wigner3j(1,0,1, cc->C+35,  pw1);
    wigner3j(1,1,0, cc->C+44,  pw0);
    wigner3j(1,1,2, cc->C+53,  pw2);
    wigner3j(1,2,1, cc->C+98,  pw1);
    wigner3j(2,0,2, cc->C+143, pw2);
    wigner3j(2,1,1, cc->C+168, pw1);
    wigner3j(2,2,0, cc->C+213, pw0);
    wigner3j(2,2,2, cc->C+238, pw2);
}

// ---------------- device ----------------
#define NTLOAD(p)  __builtin_nontemporal_load(p)

// B-phase: lanes 0..D1*K-1 each compute B[i,k] = sum_j C[i,j,k] v[j] -> LDS
template<int L1,int L2,int L3>
__device__ __forceinline__ void compute_B(const float* __restrict__ Cp,
        const float* __restrict__ vrow, float* __restrict__ Bp, int lane){
    constexpr int D1=2*L1+1, D2=2*L2+1, K=2*L3+1;
    if(lane < D1*K){
        const int i = lane / K, k = lane - i*K;
        float b = 0.f;
        #pragma unroll
        for(int j=0;j<D2;++j) b = fmaf(Cp[(i*D2+j)*K+k], vrow[j], b);
        Bp[lane] = b;   // layout i*K+k
    }
}

// A-phase: A[u,k] = sum_i u1[u,i] * B[i,k]; B read from LDS (same wave wrote it).
template<int L1,int L3,int MUL1>
__device__ __forceinline__ void compute_A(const float* __restrict__ Bp,
        const float* __restrict__ urow, float* __restrict__ As, int lane){
    constexpr int D1=2*L1+1, K=2*L3+1;
    constexpr int N = MUL1*K;
    #pragma unroll
    for(int e=lane; e<N; e+=64){
        int uu = e/K, k = e - uu*K;
        float a=0.f;
        #pragma unroll
        for(int i=0;i<D1;++i) a = fmaf(urow[uu*D1+i], Bp[i*K+k], a);
        As[e]=a;
    }
}

// Inner FMA block for one weight quad against A[u,*].
template<int K>
__device__ __forceinline__ void fma_quad(const fv4 wv,
        const float* __restrict__ Arow, int u, float (&acc)[4][K]){
    #pragma unroll
    for(int k=0;k<K;++k){
        const float a = Arow[u*K+k];
        acc[0][k] = fmaf(wv.x, a, acc[0][k]);
        acc[1][k] = fmaf(wv.y, a, acc[1][k]);
        acc[2][k] = fmaf(wv.z, a, acc[2][k]);
        acc[3][k] = fmaf(wv.w, a, acc[3][k]);
    }
}

// Linear weight-stream sweep over one path segment (nontemporal loads).
// Lane l reads wseg[256t + 4l]; w-quad fixed: q = l % (MUL3/4).
// u = (256/MUL3)*t + l/(MUL3/4). acc[c][k] += W[u, 4q+c] * A[u,k].
template<int ITERS,int MUL3,int K,int TSTART=0>
__device__ __forceinline__ void sweep(const float* __restrict__ wseg,
        const float* __restrict__ Arow, int lane, float (&acc)[4][K]){
    constexpr int GROUPS = 256/MUL3;
    const int g = lane/(MUL3/4);
    #pragma unroll
    for(int t=TSTART;t<ITERS;++t){
        const fv4 wv = NTLOAD(reinterpret_cast<const fv4*>(wseg + t*256 + 4*lane));
        fma_quad<K>(wv, Arow, GROUPS*t + g, acc);
    }
}

template<int K>
__device__ __forceinline__ void reduce_acc(float (&acc)[4][K], int firstmask){
    for(int m=firstmask; m<=32; m<<=1){
        #pragma unroll
        for(int c=0;c<4;++c)
            #pragma unroll
            for(int k=0;k<K;++k)
                acc[c][k] += __shfl_xor(acc[c][k], m);
    }
}

#define NPF 12   // prefetched float4s per wave (p0 iters 0..11, covers 12 KB of the row)

__global__ __launch_bounds__(256)
void tp_kernel(const float* __restrict__ U, const float* __restrict__ V,
               const float* __restrict__ W, float* __restrict__ Out, TPConsts cc){
    __shared__ float As[4*1184];
    __shared__ float Bs[4*128];
    const int tid = threadIdx.x, blk = blockIdx.x;
    const int lane = tid&63, wave = tid>>6;

    // Each wave owns one edge end-to-end; no cross-wave dependencies, no barriers.
    const int z = blk*4 + wave;
    const float* urow = U + (size_t)z*INDIM;
    const float* vrow = V + (size_t)z*SHDIM;
    const float* wrow = W + (size_t)z*WNUM;
    float* A  = As + wave*1184;
    float* Bw = Bs + wave*128;

    // ---- prefetch first NPF weight chunks so HBM stays busy through B/A phase ----
    fv4 pf[NPF];
    #pragma unroll
    for(int t=0;t<NPF;++t)
        pf[t] = NTLOAD(reinterpret_cast<const fv4*>(wrow + t*256 + 4*lane));

    // ---- B-phase: 115 small dots distributed over lanes ----
    compute_B<0,0,0>(cc.C+0,   vrow,   Bw+0,  lane);
    compute_B<0,1,1>(cc.C+1,   vrow+1, Bw+1,  lane);
    compute_B<0,2,2>(cc.C+10,  vrow+4, Bw+4,  lane);
    compute_B<1,0,1>(cc.C+35,  vrow,   Bw+9,  lane);
    compute_B<1,1,0>(cc.C+44,  vrow+1, Bw+18, lane);
    compute_B<1,1,2>(cc.C+53,  vrow+1, Bw+21, lane);
    compute_B<1,2,1>(cc.C+98,  vrow+4, Bw+36, lane);
    compute_B<2,0,2>(cc.C+143, vrow,   Bw+45, lane);
    compute_B<2,1,1>(cc.C+168, vrow+1, Bw+70, lane);
    compute_B<2,2,0>(cc.C+213, vrow+4, Bw+85, lane);
    compute_B<2,2,2>(cc.C+238, vrow+4, Bw+90, lane);

    // ---- A-phase: 1184 elems over 64 lanes (per-wave LDS ordering guarantees B visible) ----
    compute_A<0,0,64>(Bw+0,  urow,     A+0,    lane);
    compute_A<0,1,64>(Bw+1,  urow,     A+64,   lane);
    compute_A<0,2,64>(Bw+4,  urow,     A+256,  lane);
    compute_A<1,1,32>(Bw+9,  urow+64,  A+576,  lane);
    compute_A<1,0,32>(Bw+18, urow+64,  A+672,  lane);
    compute_A<1,2,32>(Bw+21, urow+64,  A+704,  lane);
    compute_A<1,1,32>(Bw+36, urow+64,  A+864,  lane);
    compute_A<2,2,16>(Bw+45, urow+160, A+960,  lane);
    compute_A<2,1,16>(Bw+70, urow+160, A+1040, lane);
    compute_A<2,0,16>(Bw+85, urow+160, A+1088, lane);
    compute_A<2,2,16>(Bw+90, urow+160, A+1104, lane);

    // ---- main: this wave streams its edge's full weight row linearly ----
    float acc0[4][1] = {};   // i3=0 (l3=0): lane's w-quad = lane&15
    float acc1[4][3] = {};   // i3=1 (l3=1): w-quad = lane&7
    float acc2[4][5] = {};   // i3=2 (l3=2): w-quad = lane&3

    // p0 (0,0,0): consume prefetched chunks, then the rest
    {
        const int g = lane/16;
        #pragma unroll
        for(int t=0;t<NPF;++t) fma_quad<1>(pf[t], A+0, 4*t + g, acc0);
    }
    sweep<16,64,1,NPF>(wrow+0, A+0,    lane, acc0);   // p0 tail
    sweep< 8,32,3>(wrow+4096,  A+64,   lane, acc1);   // p1 (0,1,1)
    sweep< 4,16,5>(wrow+6144,  A+256,  lane, acc2);   // p2 (0,2,2)
    sweep< 4,32,3>(wrow+7168,  A+576,  lane, acc1);   // p3 (1,0,1)
    sweep< 8,64,1>(wrow+8192,  A+672,  lane, acc0);   // p4 (1,1,0)
    sweep< 2,16,5>(wrow+10240, A+704,  lane, acc2);   // p5 (1,1,2)
    sweep< 4,32,3>(wrow+10752, A+864,  lane, acc1);   // p6 (1,2,1)
    sweep< 1,16,5>(wrow+11776, A+960,  lane, acc2);   // p7 (2,0,2)
    sweep< 2,32,3>(wrow+12032, A+1040, lane, acc1);   // p8 (2,1,1)
    sweep< 4,64,1>(wrow+12544, A+1088, lane, acc0);   // p9 (2,2,0)
    sweep< 1,16,5>(wrow+13568, A+1104, lane, acc2);   // p10 (2,2,2)

    // ---- fold lane-groups (u-dim splits) ----
    reduce_acc<1>(acc0, 16);   // 4 groups of 16
    reduce_acc<3>(acc1, 8);    // 8 groups of 8
    reduce_acc<5>(acc2, 4);    // 16 groups of 4

    // ---- stores (nontemporal) ----
    float* orow = Out + (size_t)z*OUTDIM;
    if(lane < 16){
        fv4 o; o.x=acc0[0][0]; o.y=acc0[1][0]; o.z=acc0[2][0]; o.w=acc0[3][0];
        __builtin_nontemporal_store(o, reinterpret_cast<fv4*>(orow + lane*4));
    }
    if(lane < 8){
        float* o = orow + 64 + lane*12;   // layout (4q+c)*3+k = 12q + 3c + k
        fv4 f0, f1, f2;
        f0.x=acc1[0][0]; f0.y=acc1[0][1]; f0.z=acc1[0][2]; f0.w=acc1[1][0];
        f1.x=acc1[1][1]; f1.y=acc1[1][2]; f1.z=acc1[2][0]; f1.w=acc1[2][1];
        f2.x=acc1[2][2]; f2.y=acc1[3][0]; f2.z=acc1[3][1]; f2.w=acc1[3][2];
        __builtin_nontemporal_store(f0, reinterpret_cast<fv4*>(o+0));
        __builtin_nontemporal_store(f1, reinterpret_cast<fv4*>(o+4));
        __builtin_nontemporal_store(f2, reinterpret_cast<fv4*>(o+8));
    }
    if(lane < 4){
        float* o = orow + 160 + lane*20;  // layout (4q+c)*5+k = 20q + 5c + k
        fv4 f0,f1,f2,f3;
        f0.x=acc2[0][0]; f0.y=acc2[0][1]; f0.z=acc2[0][2]; f0.w=acc2[0][3];
        f1.x=acc2[0][4]; f1.y=acc2[1][0]; f1.z=acc2[1][1]; f1.w=acc2[1][2];
        f2.x=acc2[1][3]; f2.y=acc2[1][4]; f2.z=acc2[2][0]; f2.w=acc2[2][1];
        f3.x=acc2[2][2]; f3.y=acc2[2][3]; f3.z=acc2[2][4]; f3.w=acc2[3][0];
        __builtin_nontemporal_store(f0, reinterpret_cast<fv4*>(o+0));
        __builtin_nontemporal_store(f1, reinterpret_cast<fv4*>(o+4));
        __builtin_nontemporal_store(f2, reinterpret_cast<fv4*>(o+8));
        __builtin_nontemporal_store(f3, reinterpret_cast<fv4*>(o+12));
        o[16]=acc2[3][1]; o[17]=acc2[3][2]; o[18]=acc2[3][3]; o[19]=acc2[3][4];
    }
}

extern "C" void kernel_launch(void* const* d_in, const int* in_sizes, int n_in,
                              void* d_out, int out_size, void* d_ws, size_t ws_size,
                              hipStream_t stream) {
    (void)in_sizes; (void)n_in; (void)d_ws; (void)ws_size; (void)out_size;
    const float* u = (const float*)d_in[0];
    const float* v = (const float*)d_in[1];
    const float* w = (const float*)d_in[2];
    float* out = (float*)d_out;

    TPConsts cc;
    build_consts(&cc);

    tp_kernel<<<NEDGES/4, 256, 0, stream>>>(u, v, w, out, cc);
}